// Round 2
// baseline (192.173 us; speedup 1.0000x reference)
//
#include <hip/hip_runtime.h>
#include <hip/hip_bf16.h>
#include <math.h>

#define TD 512      // D (feature dim)
#define TH 64       // H (hidden dim)
#define CHUNK 32    // rows per chunk
#define NT 256      // threads per block (4 waves)

typedef __attribute__((ext_vector_type(8))) short bf16x8;
typedef __attribute__((ext_vector_type(4))) float f32x4;

__device__ __forceinline__ unsigned short f2b(float f) {
    unsigned u = __builtin_bit_cast(unsigned, f);
    u = u + 0x7FFFu + ((u >> 16) & 1u);   // round-to-nearest-even
    return (unsigned short)(u >> 16);
}

__device__ __forceinline__ float tanh_fast(float v) {
    float e = __expf(2.0f * v);
    return 1.0f - 2.0f / (e + 1.0f);
}

// Prepass: segment offsets off[0..B], off[j] = first row index with batch >= j.
__global__ void seg_offsets_kernel(const int* __restrict__ batch32,
                                   int* __restrict__ off, int N, int B) {
    int i = blockIdx.x * blockDim.x + threadIdx.x;
    if (i >= N) return;
    const bool is64 = (batch32[N - 1] == 0);   // int64 LE => last word is a high word == 0
    auto bval = [&](int k) -> int { return is64 ? batch32[2 * k] : batch32[k]; };
    int bc = bval(i);
    if (i == 0) {
        for (int j = 0; j <= bc; ++j) off[j] = 0;
    } else {
        int bp = bval(i - 1);
        for (int j = bp + 1; j <= bc; ++j) off[j] = i;
    }
    if (i == N - 1) {
        for (int j = bc + 1; j <= B; ++j) off[j] = N;
    }
}

__global__ __launch_bounds__(NT, 2)
void attnpool_kernel(const float* __restrict__ x,
                     const float* __restrict__ W1,
                     const float* __restrict__ b1,
                     const float* __restrict__ W2,
                     const float* __restrict__ b2,
                     const int* __restrict__ off,
                     float* __restrict__ out,
                     int N)
{
    __shared__ __align__(16) unsigned short Atile[CHUNK * TD]; // bf16 bits, swizzled
    __shared__ float sP[4][CHUNK];
    __shared__ float sbuf[CHUNK];
    __shared__ float wbuf[CHUNK];
    __shared__ float outbuf[TD];
    __shared__ float mstate[4];   // 0: m_run, 1: l_run, 2: m_new, 3: alpha

    const int tid  = threadIdx.x;
    const int b    = blockIdx.x;
    const int lane = tid & 63;
    const int w    = tid >> 6;    // wave = coltile 0..3

    const int seg_start = off[b];
    const int seg_len   = off[b + 1] - seg_start;

    if (tid == 0) { mstate[0] = -INFINITY; mstate[1] = 0.0f; }
    const float b2v = b2[0];

    // ---- per-wave W1 fragments in registers (B operand, coltile = w) ----
    const int jcol = (w << 4) + (lane & 15);
    const int kb   = (lane >> 4) << 3;
    const float b1v = b1[jcol];
    const float w2v = W2[jcol];
    bf16x8 w1f[16];
    #pragma unroll
    for (int kk = 0; kk < 16; ++kk) {
        #pragma unroll
        for (int t = 0; t < 8; ++t) {
            int k = (kk << 5) + kb + t;
            w1f[kk][t] = (short)f2b(W1[k * TH + jcol]);
        }
    }

    const int rowcls = tid >> 7;          // 0..1 (row class within chunk)
    const int col4   = (tid & 127) << 2;  // feature column base (x4)

    float4 accw; accw.x = 0.f; accw.y = 0.f; accw.z = 0.f; accw.w = 0.f;
    float4 xrA[16], xrB[16];

    auto load_chunk = [&](float4 (&xr)[16], int c0) {
        #pragma unroll
        for (int p = 0; p < 16; ++p) {
            int rl = (p << 1) + rowcls;
            int r  = c0 + rl;
            int gr = (r < seg_len) ? (seg_start + r) : seg_start;  // clamp; pads get w=0
            xr[p] = *reinterpret_cast<const float4*>(&x[(size_t)gr * TD + col4]);
        }
    };

    auto body = [&](float4 (&cur)[16], float4 (&nxt)[16], int c0) {
        // prefetch FIRST so the HBM stream is continuous (loads are reg-only)
        if (c0 + CHUNK < seg_len) load_chunk(nxt, c0 + CHUNK);

        // convert + store A tile (swizzled)
        #pragma unroll
        for (int p = 0; p < 16; ++p) {
            int rl = (p << 1) + rowcls;
            ushort4 v;
            v.x = f2b(cur[p].x); v.y = f2b(cur[p].y);
            v.z = f2b(cur[p].z); v.w = f2b(cur[p].w);
            int idx = (rl * TD + col4) ^ ((rl & 7) << 3);
            *reinterpret_cast<ushort4*>(&Atile[idx]) = v;
        }
        __syncthreads();   // #1

        // MFMA: this wave covers rows 0-31 x its 16 cols, full K=512
        f32x4 acc0 = {0,0,0,0}, acc1 = {0,0,0,0};
        {
            const int rA = (lane & 15);
            const int rB = rA + 16;
            #pragma unroll
            for (int kk = 0; kk < 16; ++kk) {
                int k0 = (kk << 5) + kb;
                bf16x8 a0 = *reinterpret_cast<const bf16x8*>(&Atile[(rA * TD + k0) ^ ((rA & 7) << 3)]);
                bf16x8 a1 = *reinterpret_cast<const bf16x8*>(&Atile[(rB * TD + k0) ^ ((rB & 7) << 3)]);
                acc0 = __builtin_amdgcn_mfma_f32_16x16x32_bf16(a0, w1f[kk], acc0, 0, 0, 0);
                acc1 = __builtin_amdgcn_mfma_f32_16x16x32_bf16(a1, w1f[kk], acc1, 0, 0, 0);
            }
        }
        // bias + tanh + *W2, reduce over this wave's 16 cols
        {
            float pa[4], pb[4];
            #pragma unroll
            for (int q = 0; q < 4; ++q) {
                pa[q] = tanh_fast(acc0[q] + b1v) * w2v;
                pb[q] = tanh_fast(acc1[q] + b1v) * w2v;
            }
            #pragma unroll
            for (int m = 1; m < 16; m <<= 1) {
                #pragma unroll
                for (int q = 0; q < 4; ++q) {
                    pa[q] += __shfl_xor(pa[q], m, 64);
                    pb[q] += __shfl_xor(pb[q], m, 64);
                }
            }
            if ((lane & 15) == 0) {
                int g = lane >> 4;
                #pragma unroll
                for (int q = 0; q < 4; ++q) {
                    sP[w][(g << 2) + q]      = pa[q];
                    sP[w][16 + (g << 2) + q] = pb[q];
                }
            }
        }
        __syncthreads();   // #2

        // online softmax update
        if (tid < CHUNK) {
            int r = c0 + tid;
            float s = (r < seg_len)
                      ? (sP[0][tid] + sP[1][tid] + sP[2][tid] + sP[3][tid] + b2v)
                      : -INFINITY;
            sbuf[tid] = s;
            float mx = s;
            #pragma unroll
            for (int m = 1; m < 32; m <<= 1) mx = fmaxf(mx, __shfl_xor(mx, m, 64));
            if (tid == 0) {
                float mo = mstate[0];
                float mn = fmaxf(mo, mx);
                mstate[2] = mn;
                mstate[3] = __expf(mo - mn);   // alpha; mo=-inf -> 0
                mstate[0] = mn;
            }
        }
        __syncthreads();   // #3
        const float mn    = mstate[2];
        const float alpha = mstate[3];
        accw.x *= alpha; accw.y *= alpha; accw.z *= alpha; accw.w *= alpha;
        if (tid < CHUNK) {
            float e = __expf(sbuf[tid] - mn);   // -inf -> 0 for pad rows
            wbuf[tid] = e;
            float ls = e;
            #pragma unroll
            for (int m = 1; m < 32; m <<= 1) ls += __shfl_xor(ls, m, 64);
            if (tid == 0) mstate[1] = mstate[1] * alpha + ls;
        }
        __syncthreads();   // #4

        // weighted accumulation straight from registers (fp32 x)
        #pragma unroll
        for (int p = 0; p < 16; ++p) {
            float wgt = wbuf[(p << 1) + rowcls];
            accw.x += wgt * cur[p].x;
            accw.y += wgt * cur[p].y;
            accw.z += wgt * cur[p].z;
            accw.w += wgt * cur[p].w;
        }
    };

    __syncthreads();   // mstate ready

    if (seg_len > 0) {
        load_chunk(xrA, 0);
        int c0 = 0;
        while (true) {
            body(xrA, xrB, c0);
            c0 += CHUNK;
            if (c0 >= seg_len) break;
            body(xrB, xrA, c0);
            c0 += CHUNK;
            if (c0 >= seg_len) break;
        }
    }

    // ---- epilogue: reduce accw across the 2 row classes, normalize, store ----
    for (int g = 0; g < 2; ++g) {
        if (rowcls == g) {
            if (g == 0) {
                outbuf[col4 + 0] = accw.x; outbuf[col4 + 1] = accw.y;
                outbuf[col4 + 2] = accw.z; outbuf[col4 + 3] = accw.w;
            } else {
                outbuf[col4 + 0] += accw.x; outbuf[col4 + 1] += accw.y;
                outbuf[col4 + 2] += accw.z; outbuf[col4 + 3] += accw.w;
            }
        }
        __syncthreads();
    }
    float inv = 1.0f / (mstate[1] + 1e-16f);
    out[(size_t)b * TD + tid]       = outbuf[tid] * inv;
    out[(size_t)b * TD + 256 + tid] = outbuf[256 + tid] * inv;
}

extern "C" void kernel_launch(void* const* d_in, const int* in_sizes, int n_in,
                              void* d_out, int out_size, void* d_ws, size_t ws_size,
                              hipStream_t stream) {
    const float* x  = (const float*)d_in[0];
    const float* W1 = (const float*)d_in[1];
    const float* b1 = (const float*)d_in[2];
    const float* W2 = (const float*)d_in[3];
    const float* b2 = (const float*)d_in[4];
    const int* batch = (const int*)d_in[5];
    int N = in_sizes[5];
    int B = out_size / TD;
    if (B <= 0 || N <= 0) return;

    int* off = (int*)d_ws;   // B+1 ints
    seg_offsets_kernel<<<dim3((N + 255) / 256), dim3(256), 0, stream>>>(batch, off, N, B);
    attnpool_kernel<<<dim3(B), dim3(NT), 0, stream>>>(
        x, W1, b1, W2, b2, off, (float*)d_out, N);
}

// Round 3
// 119.802 us; speedup vs baseline: 1.6041x; 1.6041x over previous
//
#include <hip/hip_runtime.h>
#include <hip/hip_bf16.h>
#include <math.h>

#define TD 512      // D (feature dim)
#define TH 64       // H (hidden dim)
#define CHUNK 64    // rows per chunk
#define NT 512      // threads per block (8 waves)

typedef __attribute__((ext_vector_type(8))) short bf16x8;
typedef __attribute__((ext_vector_type(4))) float f32x4;

__device__ __forceinline__ unsigned short f2b(float f) {
    unsigned u = __builtin_bit_cast(unsigned, f);
    u = u + 0x7FFFu + ((u >> 16) & 1u);   // round-to-nearest-even
    return (unsigned short)(u >> 16);
}

__device__ __forceinline__ float tanh_fast(float v) {
    float e = __expf(2.0f * v);
    return 1.0f - 2.0f / (e + 1.0f);
}

// Prepass: segment offsets off[0..B], off[j] = first row index with batch >= j.
__global__ void seg_offsets_kernel(const int* __restrict__ batch32,
                                   int* __restrict__ off, int N, int B) {
    int i = blockIdx.x * blockDim.x + threadIdx.x;
    if (i >= N) return;
    const bool is64 = (batch32[N - 1] == 0);   // int64 LE => last word is high word == 0
    auto bval = [&](int k) -> int { return is64 ? batch32[2 * k] : batch32[k]; };
    int bc = bval(i);
    if (i == 0) {
        for (int j = 0; j <= bc; ++j) off[j] = 0;
    } else {
        int bp = bval(i - 1);
        for (int j = bp + 1; j <= bc; ++j) off[j] = i;
    }
    if (i == N - 1) {
        for (int j = bc + 1; j <= B; ++j) off[j] = N;
    }
}

__global__ __launch_bounds__(NT, 2)
void attnpool_kernel(const float* __restrict__ x,
                     const float* __restrict__ W1,
                     const float* __restrict__ b1,
                     const float* __restrict__ W2,
                     const float* __restrict__ b2,
                     const int* __restrict__ off,
                     float* __restrict__ out,
                     int N)
{
    __shared__ __align__(16) unsigned short W1T[TH * TD];      // bf16 bits, [col][k], swizzled
    __shared__ __align__(16) unsigned short Atile[CHUNK * TD]; // bf16 bits, [row][k], swizzled
    __shared__ float sP[4][CHUNK];
    __shared__ float outbuf4[4][TD];
    __shared__ float b1s[TH];
    __shared__ float W2s[TH];

    const int tid  = threadIdx.x;
    const int b    = blockIdx.x;
    const int lane = tid & 63;
    const int w    = tid >> 6;

    const int seg_start = off[b];
    const int seg_len   = off[b + 1] - seg_start;
    const float b2v = b2[0];

    const int rowcls = tid >> 7;          // 0..3, wave-pair uniform
    const int col4   = (tid & 127) << 2;  // feature column base (x4)
    const int ct     = w >> 1;            // coltile 0..3
    const int rt0    = (w & 1) << 1;      // rowtile base (0 or 2)

    float4 accw; accw.x = 0.f; accw.y = 0.f; accw.z = 0.f; accw.w = 0.f;
    float4 xrA[16], xrB[16];

    auto load_chunk = [&](float4 (&xr)[16], int c0) {
        #pragma unroll
        for (int p = 0; p < 16; ++p) {
            int rl = (p << 2) + rowcls;
            int r  = c0 + rl;
            int gr = (r < seg_len) ? (seg_start + r) : seg_start;  // clamp; pads get w=0
            xr[p] = *reinterpret_cast<const float4*>(&x[(size_t)gr * TD + col4]);
        }
    };

    // issue first x-chunk loads ASAP, then stage W1 while they fly
    if (seg_len > 0) load_chunk(xrA, 0);

    for (int i = 0; i < (TH * TD) / NT; ++i) {
        int e = tid + NT * i;          // flat index into W1 [k][j]
        int k = e >> 6;                // 0..511
        int j = e & 63;                // 0..63
        unsigned short v = f2b(W1[e]);
        int idx = (j * TD + k) ^ ((j & 7) << 3);
        W1T[idx] = v;
    }
    if (tid < TH) { b1s[tid] = b1[tid]; W2s[tid] = W2[tid]; }

    float m_w = -INFINITY;   // per-wave (redundant, identical across waves)
    float l_w = 0.0f;

    auto body = [&](float4 (&cur)[16], float4 (&nxt)[16], int c0) {
        // (1) prefetch FIRST so HBM stream stays continuous across chunks
        if (c0 + CHUNK < seg_len) load_chunk(nxt, c0 + CHUNK);

        // (2) convert + store A tile (swizzled)
        #pragma unroll
        for (int p = 0; p < 16; ++p) {
            int rl = (p << 2) + rowcls;
            ushort4 v;
            v.x = f2b(cur[p].x); v.y = f2b(cur[p].y);
            v.z = f2b(cur[p].z); v.w = f2b(cur[p].w);
            int idx = (rl * TD + col4) ^ ((rl & 7) << 3);
            *reinterpret_cast<ushort4*>(&Atile[idx]) = v;
        }
        __syncthreads();   // barrier #1: Atile (and W1T on first pass) ready

        // (3) MFMA: wave covers rowtiles rt0,rt0+1 x coltile ct, full K
        f32x4 acc0 = {0,0,0,0}, acc1 = {0,0,0,0};
        const int kb = (lane >> 4) << 3;
        {
            const int rA = (rt0 << 4) + (lane & 15);
            const int rB = rA + 16;
            const int cc = (ct << 4) + (lane & 15);
            #pragma unroll
            for (int kk = 0; kk < 16; ++kk) {
                int k0 = (kk << 5) + kb;
                bf16x8 bf = *reinterpret_cast<const bf16x8*>(&W1T[(cc * TD + k0) ^ ((cc & 7) << 3)]);
                bf16x8 a0 = *reinterpret_cast<const bf16x8*>(&Atile[(rA * TD + k0) ^ ((rA & 7) << 3)]);
                bf16x8 a1 = *reinterpret_cast<const bf16x8*>(&Atile[(rB * TD + k0) ^ ((rB & 7) << 3)]);
                acc0 = __builtin_amdgcn_mfma_f32_16x16x32_bf16(a0, bf, acc0, 0, 0, 0);
                acc1 = __builtin_amdgcn_mfma_f32_16x16x32_bf16(a1, bf, acc1, 0, 0, 0);
            }
        }
        // (4) bias + tanh + *W2, reduce over this wave's 16 cols, write sP
        {
            const int j = (ct << 4) + (lane & 15);
            float pa[4], pb[4];
            #pragma unroll
            for (int q = 0; q < 4; ++q) {
                pa[q] = tanh_fast(acc0[q] + b1s[j]) * W2s[j];
                pb[q] = tanh_fast(acc1[q] + b1s[j]) * W2s[j];
            }
            #pragma unroll
            for (int m = 1; m < 16; m <<= 1) {
                #pragma unroll
                for (int q = 0; q < 4; ++q) {
                    pa[q] += __shfl_xor(pa[q], m, 64);
                    pb[q] += __shfl_xor(pb[q], m, 64);
                }
            }
            if ((lane & 15) == 0) {
                int g = lane >> 4;
                #pragma unroll
                for (int q = 0; q < 4; ++q) {
                    sP[ct][(rt0 << 4) + (g << 2) + q]      = pa[q];
                    sP[ct][(rt0 << 4) + 16 + (g << 2) + q] = pb[q];
                }
            }
        }
        __syncthreads();   // barrier #2: sP ready

        // (5) per-wave redundant online softmax (no more barriers this chunk)
        {
            int r = c0 + lane;
            float s = (r < seg_len)
                      ? (sP[0][lane] + sP[1][lane] + sP[2][lane] + sP[3][lane] + b2v)
                      : -INFINITY;
            float mx = s;
            #pragma unroll
            for (int m = 1; m < 64; m <<= 1) mx = fmaxf(mx, __shfl_xor(mx, m, 64));
            float mn    = fmaxf(m_w, mx);
            float alpha = __expf(m_w - mn);      // m_w=-inf -> 0
            float ev    = __expf(s - mn);        // pad rows -> 0
            float ls = ev;
            #pragma unroll
            for (int m = 1; m < 64; m <<= 1) ls += __shfl_xor(ls, m, 64);
            l_w = l_w * alpha + ls;
            m_w = mn;

            accw.x *= alpha; accw.y *= alpha; accw.z *= alpha; accw.w *= alpha;
            // (6) weighted accumulation straight from fp32 registers
            #pragma unroll
            for (int p = 0; p < 16; ++p) {
                float wgt = __shfl(ev, (p << 2) + rowcls, 64);  // uniform src lane
                accw.x += wgt * cur[p].x;
                accw.y += wgt * cur[p].y;
                accw.z += wgt * cur[p].z;
                accw.w += wgt * cur[p].w;
            }
        }
    };

    if (seg_len > 0) {
        int c0 = 0;
        while (true) {
            body(xrA, xrB, c0);
            c0 += CHUNK;
            if (c0 >= seg_len) break;
            body(xrB, xrA, c0);
            c0 += CHUNK;
            if (c0 >= seg_len) break;
        }
    }

    // ---- epilogue: one-barrier reduction across the 4 row classes ----
    outbuf4[rowcls][col4 + 0] = accw.x;
    outbuf4[rowcls][col4 + 1] = accw.y;
    outbuf4[rowcls][col4 + 2] = accw.z;
    outbuf4[rowcls][col4 + 3] = accw.w;
    __syncthreads();
    float inv = 1.0f / (l_w + 1e-16f);
    out[(size_t)b * TD + tid] =
        (outbuf4[0][tid] + outbuf4[1][tid] + outbuf4[2][tid] + outbuf4[3][tid]) * inv;
}

extern "C" void kernel_launch(void* const* d_in, const int* in_sizes, int n_in,
                              void* d_out, int out_size, void* d_ws, size_t ws_size,
                              hipStream_t stream) {
    const float* x  = (const float*)d_in[0];
    const float* W1 = (const float*)d_in[1];
    const float* b1 = (const float*)d_in[2];
    const float* W2 = (const float*)d_in[3];
    const float* b2 = (const float*)d_in[4];
    const int* batch = (const int*)d_in[5];
    int N = in_sizes[5];
    int B = out_size / TD;
    if (B <= 0 || N <= 0) return;

    int* off = (int*)d_ws;   // B+1 ints
    seg_offsets_kernel<<<dim3((N + 255) / 256), dim3(256), 0, stream>>>(batch, off, N, B);
    attnpool_kernel<<<dim3(B), dim3(NT), 0, stream>>>(
        x, W1, b1, W2, b2, off, (float*)d_out, N);
}